// Round 21
// baseline (62.524 us; speedup 1.0000x reference)
//
#include <hip/hip_runtime.h>
#include <hip/hip_bf16.h>

typedef __attribute__((ext_vector_type(8))) short short8;
typedef __attribute__((ext_vector_type(4))) float f32x4;
typedef __attribute__((ext_vector_type(16))) float f32x16;
typedef __attribute__((ext_vector_type(2))) int int2v;

#define N_TOK 8192
#define D_HALF 64
#define D_FULL 128
#define QB 128                     // q rows per block (4 sub-tiles of 32)
#define KQ 2048                    // keys per block (k-split 4)
#define CHUNK 128                  // keys staged per chunk (32KB K + 32KB V)
#define NCH (KQ / CHUNK)           // 16
#define OSTR 132
#define RSC 1.2011224087864498f    // sqrt(log2(e)): scores arrive in log2 domain
#define MFIX 94.0f                 // fixed softmax max: > 64*log2(e)=92.33 bound

// pack two f32 into one bf16x2 word (lo=a, hi=b) -- single v_cvt_pk_bf16_f32
static __device__ __forceinline__ unsigned cvtpk(float a, float b)
{
    unsigned r;
    asm("v_cvt_pk_bf16_f32 %0, %1, %2" : "=v"(r) : "v"(a), "v"(b));
    return r;
}

// raw native exp2 (scores are <= -1.7 here; <= -126 flushes to 0, fine)
static __device__ __forceinline__ float exp2raw(float x)
{
    float r;
    asm("v_exp_f32 %0, %1" : "=v"(r) : "v"(x));
    return r;
}

// Fused precompute, vectorized 16B stores (R19, verified).
__global__ __launch_bounds__(256) void precompute_kernel(
    const float* __restrict__ mag, const float* __restrict__ phase,
    __hip_bfloat16* __restrict__ Kf, __hip_bfloat16* __restrict__ Vf)
{
    const int bid = blockIdx.x;
    const int tid = threadIdx.x;

    if (bid < 256) {
        // ---- K-pack ----
        int g  = bid * 256 + tid;        // 65536 threads
        int n  = g >> 3;
        int db = g & 7;
        const f32x4* mp = reinterpret_cast<const f32x4*>(mag + (size_t)n * 64 + db * 8);
        const f32x4* pp = reinterpret_cast<const f32x4*>(phase + (size_t)n * 64 + db * 8);
        f32x4 m0 = mp[0], m1 = mp[1];
        f32x4 p0 = pp[0], p1 = pp[1];
        float kc[8], ks_[8];
        #pragma unroll
        for (int j = 0; j < 4; ++j) {
            float s, c;
            sincosf(p0[j], &s, &c);
            kc[j]  = m0[j] * c * RSC;
            ks_[j] = m0[j] * s * RSC;
        }
        #pragma unroll
        for (int j = 0; j < 4; ++j) {
            float s, c;
            sincosf(p1[j], &s, &c);
            kc[4 + j]  = m1[j] * c * RSC;
            ks_[4 + j] = m1[j] * s * RSC;
        }
        union { unsigned w[4]; short8 v; } vc, vs;
        #pragma unroll
        for (int j = 0; j < 4; ++j) {
            vc.w[j] = cvtpk(kc[2 * j], kc[2 * j + 1]);
            vs.w[j] = cvtpk(ks_[2 * j], ks_[2 * j + 1]);
        }
        short8* K8 = reinterpret_cast<short8*>(Kf);
        int offc = ((n >> 5) * 16 + db) * 32 + (n & 31);       // short8 units
        int offs = ((n >> 5) * 16 + 8 + db) * 32 + (n & 31);
        K8[offc] = vc.v;
        K8[offs] = vs.v;
    } else {
        // ---- V-pack (LDS transpose; no trig) ----
        __shared__ float T[32][65];
        int vb   = bid - 256;            // 0..511
        int tile = vb >> 1;              // 0..255 (32-row tiles)
        int h    = vb & 1;               // 0 = mag, 1 = phase
        const float* src = h ? phase : mag;
        {
            int r = tid >> 3, cp = (tid & 7) * 8;
            const f32x4* sp = reinterpret_cast<const f32x4*>(src + ((size_t)tile * 32 + r) * 64 + cp);
            f32x4 a = sp[0], b = sp[1];
            #pragma unroll
            for (int j = 0; j < 4; ++j) { T[r][cp + j] = a[j]; T[r][cp + 4 + j] = b[j]; }
        }
        __syncthreads();

        int dv = tid & 63;
        int nb = tid >> 6;
        int n0 = tile * 32 + nb * 8;
        int dv_eff = dv + 64 * h;
        union { unsigned w[4]; short8 v; } pk;
        #pragma unroll
        for (int j = 0; j < 4; ++j)
            pk.w[j] = cvtpk(T[nb * 8 + 2 * j][dv], T[nb * 8 + 2 * j + 1][dv]);
        short8* V8 = reinterpret_cast<short8*>(Vf);
        int off8 = ((n0 >> 4) * 4 + (dv_eff >> 5)) * 64 + ((n0 >> 3) & 1) * 32 + (dv_eff & 31);
        V8[off8] = pk.v;
    }
}

// R20 structure + ROUND-21 change: QK accumulator split 2 -> 4 independent
// chains (sa/sb/sc/sd, 2-deep each). R20's 1->2 split gained 8.7us by
// covering dependent-MFMA latency; 4 chains x 2 waves = 8 independent
// streams/SIMD fully covers ~32cy latency at 8cy issue.
// Fixed-max softmax, raw v_exp_f32, counted-vmcnt DMA, bf16 partials.
__global__ __launch_bounds__(512, 2) void attn_kernel(
    const short8* __restrict__ Kf8, const short8* __restrict__ Vf8,
    __hip_bfloat16* __restrict__ Opart, float* __restrict__ Sp)
{
    __shared__ __align__(16) char smem[132096];  // 2 x (K 32KB | V 32KB) + merge sums

    const int tid  = threadIdx.x;
    const int wid  = tid >> 6;     // 0..7
    const int lane = tid & 63;
    const int li   = lane & 31;
    const int hi   = lane >> 5;
    const int qh   = wid >> 1;     // q sub-tile 0..3
    const int kp   = wid & 1;      // key panel group

    const int bid  = blockIdx.x;
    const int qt   = bid >> 2;     // 0..63
    const int kq   = bid & 3;      // key quarter
    const int rot  = bid & (NCH - 1);

    float (*O_lds)[32][OSTR] = (float (*)[32][OSTR])smem;   // merge reuse
    float* s_base = (float*)(smem + 67584);                 // [4][32]
    auto sslot = [&](int slot) -> float* { return s_base + slot * 32; };

    auto stageKV = [&](int ck, char* lbase) {
        const char* gk = (const char*)(Kf8 + (size_t)ck * 2048);
        const char* gv = (const char*)(Vf8 + (size_t)ck * 2048);
        #pragma unroll
        for (int j = 0; j < 4; ++j)
            __builtin_amdgcn_global_load_lds(
                (const __attribute__((address_space(1))) void*)(gk + j * 8192 + tid * 16),
                (__attribute__((address_space(3))) void*)(lbase + j * 8192 + tid * 16),
                16, 0, 0);
        #pragma unroll
        for (int j = 0; j < 4; ++j)
            __builtin_amdgcn_global_load_lds(
                (const __attribute__((address_space(1))) void*)(gv + j * 8192 + tid * 16),
                (__attribute__((address_space(3))) void*)(lbase + 32768 + j * 8192 + tid * 16),
                16, 0, 0);
    };
    auto ck_of = [&](int t) { return kq * NCH + ((t + rot) & (NCH - 1)); };

    // Q fragments FIRST (oldest in vmcnt queue, so counted waits stay exact)
    short8 bq[8];
    {
        const short8* qp = Kf8 + (size_t)(qt * 4 + qh) * 512;
        #pragma unroll
        for (int ks = 0; ks < 8; ++ks)
            bq[ks] = qp[(ks * 2 + hi) * 32 + li];
    }

    f32x16 acc[4];
    #pragma unroll
    for (int d = 0; d < 4; ++d) acc[d] = (f32x16)(0.0f);
    float srow = 0.0f;

    stageKV(ck_of(0), smem);
    stageKV(ck_of(1), smem + 65536);
    asm volatile("s_waitcnt vmcnt(8)");     // bq + S(0) retired; S(1) flying
    __builtin_amdgcn_s_barrier();

    for (int t = 0; t < NCH; ++t) {
        char* base = smem + (t & 1) * 65536;
        const short8* ldsK = (const short8*)base;
        const short8* ldsV = (const short8*)(base + 32768);

        #pragma unroll
        for (int pp = 0; pp < 2; ++pp) {
            const int panel = kp + 2 * pp;

            // ---- S^T = K.Q: FOUR independent 2-deep chains ----
            f32x16 sa = (f32x16)(-MFIX);   // C-init folds the softmax subtract
            f32x16 sb = (f32x16)(0.0f);
            f32x16 sc = (f32x16)(0.0f);
            f32x16 sd = (f32x16)(0.0f);
            __builtin_amdgcn_s_setprio(1);
            #pragma unroll
            for (int ks = 0; ks < 2; ++ks) {
                short8 kfa = ldsK[panel * 512 + (ks * 2 + hi) * 32 + li];
                short8 kfb = ldsK[panel * 512 + ((ks + 2) * 2 + hi) * 32 + li];
                short8 kfc = ldsK[panel * 512 + ((ks + 4) * 2 + hi) * 32 + li];
                short8 kfd = ldsK[panel * 512 + ((ks + 6) * 2 + hi) * 32 + li];
                sa = __builtin_amdgcn_mfma_f32_32x32x16_bf16(kfa, bq[ks], sa, 0, 0, 0);
                sb = __builtin_amdgcn_mfma_f32_32x32x16_bf16(kfb, bq[ks + 2], sb, 0, 0, 0);
                sc = __builtin_amdgcn_mfma_f32_32x32x16_bf16(kfc, bq[ks + 4], sc, 0, 0, 0);
                sd = __builtin_amdgcn_mfma_f32_32x32x16_bf16(kfd, bq[ks + 6], sd, 0, 0, 0);
            }
            __builtin_amdgcn_s_setprio(0);
            f32x16 st;
            #pragma unroll
            for (int r = 0; r < 16; ++r) st[r] = (sa[r] + sb[r]) + (sc[r] + sd[r]);

            // ---- P = exp2(st) (native v_exp_f32); row-sum only ----
            #pragma unroll
            for (int r = 0; r < 16; ++r) st[r] = exp2raw(st[r]);
            float sm[8];
            #pragma unroll
            for (int r = 0; r < 8; ++r) sm[r] = st[r] + st[r + 8];
            float ss = ((sm[0] + sm[1]) + (sm[2] + sm[3]))
                     + ((sm[4] + sm[5]) + (sm[6] + sm[7]));
            srow += ss + __shfl_xor(ss, 32);

            // ---- PV: pack P (cvt_pk) -> permlane repack -> 8 MFMA ----
            #pragma unroll
            for (int c = 0; c < 2; ++c) {
                const int b = 8 * c;
                unsigned a0 = cvtpk(st[b + 0], st[b + 1]);
                unsigned a1 = cvtpk(st[b + 2], st[b + 3]);
                unsigned b0 = cvtpk(st[b + 4], st[b + 5]);
                unsigned b1 = cvtpk(st[b + 6], st[b + 7]);
                int2v r0 = __builtin_amdgcn_permlane32_swap((int)a0, (int)b0, false, false);
                int2v r1 = __builtin_amdgcn_permlane32_swap((int)a1, (int)b1, false, false);
                union { int w[4]; short8 v; } u;
                u.w[0] = r0[0]; u.w[1] = r1[0]; u.w[2] = r0[1]; u.w[3] = r1[1];

                const short8* vp = ldsV + (panel * 2 + c) * 256 + hi * 32 + li;
                __builtin_amdgcn_s_setprio(1);
                #pragma unroll
                for (int d = 0; d < 4; ++d) {
                    short8 vf = vp[d * 64];
                    acc[d] = __builtin_amdgcn_mfma_f32_32x32x16_bf16(vf, u.v, acc[d], 0, 0, 0);
                }
                __builtin_amdgcn_s_setprio(0);
            }
        }

        __builtin_amdgcn_s_barrier();            // all waves done reading buf
        if (t + 2 < NCH) {
            stageKV(ck_of(t + 2), base);         // refill this buffer
            asm volatile("s_waitcnt vmcnt(8)");  // S(t+1) landed, S(t+2) flying
        } else {
            asm volatile("s_waitcnt vmcnt(0)");  // epilogue drain
        }
        __builtin_amdgcn_s_barrier();            // next buffer ready for all
    }

    // ---- in-block merge over kp (pure sums; fixed max everywhere) ----
    auto store_partial = [&](int slot) {
        #pragma unroll
        for (int d = 0; d < 4; ++d)
            #pragma unroll
            for (int rr = 0; rr < 4; ++rr) {
                f32x4 v;
                #pragma unroll
                for (int j = 0; j < 4; ++j) v[j] = acc[d][4 * rr + j];
                *reinterpret_cast<f32x4*>(&O_lds[slot][li][d * 32 + 8 * rr + 4 * hi]) = v;
            }
        if (hi == 0) sslot(slot)[li] = srow;
    };
    auto merge_partial = [&](int slot) {
        srow += sslot(slot)[li];
        #pragma unroll
        for (int d = 0; d < 4; ++d)
            #pragma unroll
            for (int rr = 0; rr < 4; ++rr) {
                f32x4 v = *reinterpret_cast<const f32x4*>(&O_lds[slot][li][d * 32 + 8 * rr + 4 * hi]);
                #pragma unroll
                for (int j = 0; j < 4; ++j)
                    acc[d][4 * rr + j] += v[j];
            }
    };

    __syncthreads();                         // staging dead; reuse as merge space
    if (kp == 1) store_partial(qh);
    __syncthreads();
    if (kp == 0) merge_partial(qh);
    __syncthreads();
    if (kp == 0) store_partial(qh);
    __syncthreads();

    // ---- write UNNORMALIZED per-block partial as bf16 ----
    #pragma unroll
    for (int u0 = 0; u0 < 4; ++u0) {
        int u  = tid + u0 * 512;           // 0..2047
        int q  = u >> 4;                   // 0..127
        int dg = (u & 15) * 8;             // 0..120
        int grp = q >> 5, qq = q & 31;
        f32x4 o0 = *reinterpret_cast<const f32x4*>(&O_lds[grp][qq][dg]);
        f32x4 o1 = *reinterpret_cast<const f32x4*>(&O_lds[grp][qq][dg + 4]);
        union { unsigned w[4]; short8 v; } pk;
        pk.w[0] = cvtpk(o0[0], o0[1]);
        pk.w[1] = cvtpk(o0[2], o0[3]);
        pk.w[2] = cvtpk(o1[0], o1[1]);
        pk.w[3] = cvtpk(o1[2], o1[3]);
        size_t pidx = (size_t)bid * QB + q;
        *reinterpret_cast<short8*>(&Opart[pidx * D_FULL + dg]) = pk.v;
        if (dg == 0) Sp[pidx] = sslot(grp)[qq];   // merged sum from LDS (f32)
    }
}

// combine the four k-quarter bf16 partials per q-row (pure sums), normalize
__global__ __launch_bounds__(256) void merge4_kernel(
    const __hip_bfloat16* __restrict__ Opart, const float* __restrict__ Sp,
    float* __restrict__ out)
{
    int i   = blockIdx.x * 256 + threadIdx.x;   // 131072 total, 8 floats each
    int row = i >> 4;                           // 0..8191
    int dg  = (i & 15) * 8;                     // 0..120
    int qt  = row >> 7, qq = row & 127;
    float S = 0.0f;
    f32x4 o0 = (f32x4)(0.0f), o1 = (f32x4)(0.0f);
    #pragma unroll
    for (int k = 0; k < 4; ++k) {
        size_t pidx = (size_t)(qt * 4 + k) * QB + qq;
        S += Sp[pidx];
        short8 v = *reinterpret_cast<const short8*>(&Opart[pidx * D_FULL + dg]);
        #pragma unroll
        for (int j = 0; j < 8; ++j) {
            unsigned short us = (unsigned short)v[j];
            unsigned wu = ((unsigned)us) << 16;
            float f = *reinterpret_cast<float*>(&wu);
            if (j < 4) o0[j] += f; else o1[j - 4] += f;
        }
    }
    float inv = 1.0f / S;
    #pragma unroll
    for (int j = 0; j < 4; ++j) { o0[j] *= inv; o1[j] *= inv; }
    float* dst = (dg < D_HALF)
        ? out + (size_t)row * D_HALF + dg
        : out + (size_t)N_TOK * D_HALF + (size_t)row * D_HALF + (dg - D_HALF);
    *reinterpret_cast<f32x4*>(dst)     = o0;
    *reinterpret_cast<f32x4*>(dst + 4) = o1;
}

extern "C" void kernel_launch(void* const* d_in, const int* in_sizes, int n_in,
                              void* d_out, int out_size, void* d_ws, size_t ws_size,
                              hipStream_t stream)
{
    const float* mag   = (const float*)d_in[0];
    const float* phase = (const float*)d_in[1];
    float* out = (float*)d_out;

    char* ws = (char*)d_ws;
    __hip_bfloat16* Kf = (__hip_bfloat16*)ws;                    // 2 MB
    __hip_bfloat16* Vf = Kf + (size_t)N_TOK * D_FULL;            // 2 MB
    __hip_bfloat16* Opart = (__hip_bfloat16*)(ws + 4u * 1024 * 1024);  // 8 MB
    float* Sp = (float*)(ws + 13u * 1024 * 1024);                // 128 KB

    precompute_kernel<<<768, 256, 0, stream>>>(mag, phase, Kf, Vf);
    attn_kernel<<<256, 512, 0, stream>>>((const short8*)Kf, (const short8*)Vf, Opart, Sp);
    merge4_kernel<<<512, 256, 0, stream>>>(Opart, Sp, out);
}

// Round 22
// 55.128 us; speedup vs baseline: 1.1342x; 1.1342x over previous
//
#include <hip/hip_runtime.h>
#include <hip/hip_bf16.h>

typedef __attribute__((ext_vector_type(8))) short short8;
typedef __attribute__((ext_vector_type(4))) float f32x4;
typedef __attribute__((ext_vector_type(16))) float f32x16;
typedef __attribute__((ext_vector_type(2))) int int2v;

#define N_TOK 8192
#define D_HALF 64
#define D_FULL 128
#define QB 128                     // q rows per block (4 sub-tiles of 32)
#define KQ 2048                    // keys per block (k-split 4)
#define CHUNK 128                  // keys staged per chunk (32KB K + 32KB V)
#define NCH (KQ / CHUNK)           // 16
#define OSTR 132
#define RSC 1.2011224087864498f    // sqrt(log2(e)): scores arrive in log2 domain
#define MFIX 94.0f                 // fixed softmax max: > 64*log2(e)=92.33 bound

// pack two f32 into one bf16x2 word (lo=a, hi=b) -- single v_cvt_pk_bf16_f32
static __device__ __forceinline__ unsigned cvtpk(float a, float b)
{
    unsigned r;
    asm("v_cvt_pk_bf16_f32 %0, %1, %2" : "=v"(r) : "v"(a), "v"(b));
    return r;
}

// raw native exp2 (scores are <= -1.7 here; <= -126 flushes to 0, fine)
static __device__ __forceinline__ float exp2raw(float x)
{
    float r;
    asm("v_exp_f32 %0, %1" : "=v"(r) : "v"(x));
    return r;
}

// Fused precompute, vectorized 16B stores (R19, verified).
__global__ __launch_bounds__(256) void precompute_kernel(
    const float* __restrict__ mag, const float* __restrict__ phase,
    __hip_bfloat16* __restrict__ Kf, __hip_bfloat16* __restrict__ Vf)
{
    const int bid = blockIdx.x;
    const int tid = threadIdx.x;

    if (bid < 256) {
        // ---- K-pack ----
        int g  = bid * 256 + tid;        // 65536 threads
        int n  = g >> 3;
        int db = g & 7;
        const f32x4* mp = reinterpret_cast<const f32x4*>(mag + (size_t)n * 64 + db * 8);
        const f32x4* pp = reinterpret_cast<const f32x4*>(phase + (size_t)n * 64 + db * 8);
        f32x4 m0 = mp[0], m1 = mp[1];
        f32x4 p0 = pp[0], p1 = pp[1];
        float kc[8], ks_[8];
        #pragma unroll
        for (int j = 0; j < 4; ++j) {
            float s, c;
            sincosf(p0[j], &s, &c);
            kc[j]  = m0[j] * c * RSC;
            ks_[j] = m0[j] * s * RSC;
        }
        #pragma unroll
        for (int j = 0; j < 4; ++j) {
            float s, c;
            sincosf(p1[j], &s, &c);
            kc[4 + j]  = m1[j] * c * RSC;
            ks_[4 + j] = m1[j] * s * RSC;
        }
        union { unsigned w[4]; short8 v; } vc, vs;
        #pragma unroll
        for (int j = 0; j < 4; ++j) {
            vc.w[j] = cvtpk(kc[2 * j], kc[2 * j + 1]);
            vs.w[j] = cvtpk(ks_[2 * j], ks_[2 * j + 1]);
        }
        short8* K8 = reinterpret_cast<short8*>(Kf);
        int offc = ((n >> 5) * 16 + db) * 32 + (n & 31);       // short8 units
        int offs = ((n >> 5) * 16 + 8 + db) * 32 + (n & 31);
        K8[offc] = vc.v;
        K8[offs] = vs.v;
    } else {
        // ---- V-pack (LDS transpose; no trig) ----
        __shared__ float T[32][65];
        int vb   = bid - 256;            // 0..511
        int tile = vb >> 1;              // 0..255 (32-row tiles)
        int h    = vb & 1;               // 0 = mag, 1 = phase
        const float* src = h ? phase : mag;
        {
            int r = tid >> 3, cp = (tid & 7) * 8;
            const f32x4* sp = reinterpret_cast<const f32x4*>(src + ((size_t)tile * 32 + r) * 64 + cp);
            f32x4 a = sp[0], b = sp[1];
            #pragma unroll
            for (int j = 0; j < 4; ++j) { T[r][cp + j] = a[j]; T[r][cp + 4 + j] = b[j]; }
        }
        __syncthreads();

        int dv = tid & 63;
        int nb = tid >> 6;
        int n0 = tile * 32 + nb * 8;
        int dv_eff = dv + 64 * h;
        union { unsigned w[4]; short8 v; } pk;
        #pragma unroll
        for (int j = 0; j < 4; ++j)
            pk.w[j] = cvtpk(T[nb * 8 + 2 * j][dv], T[nb * 8 + 2 * j + 1][dv]);
        short8* V8 = reinterpret_cast<short8*>(Vf);
        int off8 = ((n0 >> 4) * 4 + (dv_eff >> 5)) * 64 + ((n0 >> 3) & 1) * 32 + (dv_eff & 31);
        V8[off8] = pk.v;
    }
}

// R20 structure (measured best: 47.4us attn / 54.7us total).
// - counted-vmcnt double-buffer DMA pipeline (stage(t+2), vmcnt(8))
// - fixed-max softmax: scores bounded by 64*log2e<94 in log2 domain ->
//   no running max/rescale; subtract folded into MFMA C-init
// - QK accumulator split into TWO independent 4-deep chains (R20: 1->2
//   chains = +8.7us; R21 showed 4 chains regresses via register pressure)
// - raw v_exp_f32, cvt_pk+permlane P repack, bf16 partials, pure-sum merges
__global__ __launch_bounds__(512, 2) void attn_kernel(
    const short8* __restrict__ Kf8, const short8* __restrict__ Vf8,
    __hip_bfloat16* __restrict__ Opart, float* __restrict__ Sp)
{
    __shared__ __align__(16) char smem[132096];  // 2 x (K 32KB | V 32KB) + merge sums

    const int tid  = threadIdx.x;
    const int wid  = tid >> 6;     // 0..7
    const int lane = tid & 63;
    const int li   = lane & 31;
    const int hi   = lane >> 5;
    const int qh   = wid >> 1;     // q sub-tile 0..3
    const int kp   = wid & 1;      // key panel group

    const int bid  = blockIdx.x;
    const int qt   = bid >> 2;     // 0..63
    const int kq   = bid & 3;      // key quarter
    const int rot  = bid & (NCH - 1);

    float (*O_lds)[32][OSTR] = (float (*)[32][OSTR])smem;   // merge reuse
    float* s_base = (float*)(smem + 67584);                 // [4][32]
    auto sslot = [&](int slot) -> float* { return s_base + slot * 32; };

    auto stageKV = [&](int ck, char* lbase) {
        const char* gk = (const char*)(Kf8 + (size_t)ck * 2048);
        const char* gv = (const char*)(Vf8 + (size_t)ck * 2048);
        #pragma unroll
        for (int j = 0; j < 4; ++j)
            __builtin_amdgcn_global_load_lds(
                (const __attribute__((address_space(1))) void*)(gk + j * 8192 + tid * 16),
                (__attribute__((address_space(3))) void*)(lbase + j * 8192 + tid * 16),
                16, 0, 0);
        #pragma unroll
        for (int j = 0; j < 4; ++j)
            __builtin_amdgcn_global_load_lds(
                (const __attribute__((address_space(1))) void*)(gv + j * 8192 + tid * 16),
                (__attribute__((address_space(3))) void*)(lbase + 32768 + j * 8192 + tid * 16),
                16, 0, 0);
    };
    auto ck_of = [&](int t) { return kq * NCH + ((t + rot) & (NCH - 1)); };

    // Q fragments FIRST (oldest in vmcnt queue, so counted waits stay exact)
    short8 bq[8];
    {
        const short8* qp = Kf8 + (size_t)(qt * 4 + qh) * 512;
        #pragma unroll
        for (int ks = 0; ks < 8; ++ks)
            bq[ks] = qp[(ks * 2 + hi) * 32 + li];
    }

    f32x16 acc[4];
    #pragma unroll
    for (int d = 0; d < 4; ++d) acc[d] = (f32x16)(0.0f);
    float srow = 0.0f;

    stageKV(ck_of(0), smem);
    stageKV(ck_of(1), smem + 65536);
    asm volatile("s_waitcnt vmcnt(8)");     // bq + S(0) retired; S(1) flying
    __builtin_amdgcn_s_barrier();

    for (int t = 0; t < NCH; ++t) {
        char* base = smem + (t & 1) * 65536;
        const short8* ldsK = (const short8*)base;
        const short8* ldsV = (const short8*)(base + 32768);

        #pragma unroll
        for (int pp = 0; pp < 2; ++pp) {
            const int panel = kp + 2 * pp;

            // ---- S^T = K.Q: TWO independent 4-deep chains ----
            f32x16 sa = (f32x16)(-MFIX);   // C-init folds the softmax subtract
            f32x16 sb = (f32x16)(0.0f);
            __builtin_amdgcn_s_setprio(1);
            #pragma unroll
            for (int ks = 0; ks < 4; ++ks) {
                short8 kfa = ldsK[panel * 512 + (ks * 2 + hi) * 32 + li];
                short8 kfb = ldsK[panel * 512 + ((ks + 4) * 2 + hi) * 32 + li];
                sa = __builtin_amdgcn_mfma_f32_32x32x16_bf16(kfa, bq[ks], sa, 0, 0, 0);
                sb = __builtin_amdgcn_mfma_f32_32x32x16_bf16(kfb, bq[ks + 4], sb, 0, 0, 0);
            }
            __builtin_amdgcn_s_setprio(0);
            f32x16 st;
            #pragma unroll
            for (int r = 0; r < 16; ++r) st[r] = sa[r] + sb[r];

            // ---- P = exp2(st) (native v_exp_f32); row-sum only ----
            #pragma unroll
            for (int r = 0; r < 16; ++r) st[r] = exp2raw(st[r]);
            float sm[8];
            #pragma unroll
            for (int r = 0; r < 8; ++r) sm[r] = st[r] + st[r + 8];
            float ss = ((sm[0] + sm[1]) + (sm[2] + sm[3]))
                     + ((sm[4] + sm[5]) + (sm[6] + sm[7]));
            srow += ss + __shfl_xor(ss, 32);

            // ---- PV: pack P (cvt_pk) -> permlane repack -> 8 MFMA ----
            #pragma unroll
            for (int c = 0; c < 2; ++c) {
                const int b = 8 * c;
                unsigned a0 = cvtpk(st[b + 0], st[b + 1]);
                unsigned a1 = cvtpk(st[b + 2], st[b + 3]);
                unsigned b0 = cvtpk(st[b + 4], st[b + 5]);
                unsigned b1 = cvtpk(st[b + 6], st[b + 7]);
                int2v r0 = __builtin_amdgcn_permlane32_swap((int)a0, (int)b0, false, false);
                int2v r1 = __builtin_amdgcn_permlane32_swap((int)a1, (int)b1, false, false);
                union { int w[4]; short8 v; } u;
                u.w[0] = r0[0]; u.w[1] = r1[0]; u.w[2] = r0[1]; u.w[3] = r1[1];

                const short8* vp = ldsV + (panel * 2 + c) * 256 + hi * 32 + li;
                __builtin_amdgcn_s_setprio(1);
                #pragma unroll
                for (int d = 0; d < 4; ++d) {
                    short8 vf = vp[d * 64];
                    acc[d] = __builtin_amdgcn_mfma_f32_32x32x16_bf16(vf, u.v, acc[d], 0, 0, 0);
                }
                __builtin_amdgcn_s_setprio(0);
            }
        }

        __builtin_amdgcn_s_barrier();            // all waves done reading buf
        if (t + 2 < NCH) {
            stageKV(ck_of(t + 2), base);         // refill this buffer
            asm volatile("s_waitcnt vmcnt(8)");  // S(t+1) landed, S(t+2) flying
        } else {
            asm volatile("s_waitcnt vmcnt(0)");  // epilogue drain
        }
        __builtin_amdgcn_s_barrier();            // next buffer ready for all
    }

    // ---- in-block merge over kp (pure sums; fixed max everywhere) ----
    auto store_partial = [&](int slot) {
        #pragma unroll
        for (int d = 0; d < 4; ++d)
            #pragma unroll
            for (int rr = 0; rr < 4; ++rr) {
                f32x4 v;
                #pragma unroll
                for (int j = 0; j < 4; ++j) v[j] = acc[d][4 * rr + j];
                *reinterpret_cast<f32x4*>(&O_lds[slot][li][d * 32 + 8 * rr + 4 * hi]) = v;
            }
        if (hi == 0) sslot(slot)[li] = srow;
    };
    auto merge_partial = [&](int slot) {
        srow += sslot(slot)[li];
        #pragma unroll
        for (int d = 0; d < 4; ++d)
            #pragma unroll
            for (int rr = 0; rr < 4; ++rr) {
                f32x4 v = *reinterpret_cast<const f32x4*>(&O_lds[slot][li][d * 32 + 8 * rr + 4 * hi]);
                #pragma unroll
                for (int j = 0; j < 4; ++j)
                    acc[d][4 * rr + j] += v[j];
            }
    };

    __syncthreads();                         // staging dead; reuse as merge space
    if (kp == 1) store_partial(qh);
    __syncthreads();
    if (kp == 0) merge_partial(qh);
    __syncthreads();
    if (kp == 0) store_partial(qh);
    __syncthreads();

    // ---- write UNNORMALIZED per-block partial as bf16 ----
    #pragma unroll
    for (int u0 = 0; u0 < 4; ++u0) {
        int u  = tid + u0 * 512;           // 0..2047
        int q  = u >> 4;                   // 0..127
        int dg = (u & 15) * 8;             // 0..120
        int grp = q >> 5, qq = q & 31;
        f32x4 o0 = *reinterpret_cast<const f32x4*>(&O_lds[grp][qq][dg]);
        f32x4 o1 = *reinterpret_cast<const f32x4*>(&O_lds[grp][qq][dg + 4]);
        union { unsigned w[4]; short8 v; } pk;
        pk.w[0] = cvtpk(o0[0], o0[1]);
        pk.w[1] = cvtpk(o0[2], o0[3]);
        pk.w[2] = cvtpk(o1[0], o1[1]);
        pk.w[3] = cvtpk(o1[2], o1[3]);
        size_t pidx = (size_t)bid * QB + q;
        *reinterpret_cast<short8*>(&Opart[pidx * D_FULL + dg]) = pk.v;
        if (dg == 0) Sp[pidx] = sslot(grp)[qq];   // merged sum from LDS (f32)
    }
}

// combine the four k-quarter bf16 partials per q-row (pure sums), normalize
__global__ __launch_bounds__(256) void merge4_kernel(
    const __hip_bfloat16* __restrict__ Opart, const float* __restrict__ Sp,
    float* __restrict__ out)
{
    int i   = blockIdx.x * 256 + threadIdx.x;   // 131072 total, 8 floats each
    int row = i >> 4;                           // 0..8191
    int dg  = (i & 15) * 8;                     // 0..120
    int qt  = row >> 7, qq = row & 127;
    float S = 0.0f;
    f32x4 o0 = (f32x4)(0.0f), o1 = (f32x4)(0.0f);
    #pragma unroll
    for (int k = 0; k < 4; ++k) {
        size_t pidx = (size_t)(qt * 4 + k) * QB + qq;
        S += Sp[pidx];
        short8 v = *reinterpret_cast<const short8*>(&Opart[pidx * D_FULL + dg]);
        #pragma unroll
        for (int j = 0; j < 8; ++j) {
            unsigned short us = (unsigned short)v[j];
            unsigned wu = ((unsigned)us) << 16;
            float f = *reinterpret_cast<float*>(&wu);
            if (j < 4) o0[j] += f; else o1[j - 4] += f;
        }
    }
    float inv = 1.0f / S;
    #pragma unroll
    for (int j = 0; j < 4; ++j) { o0[j] *= inv; o1[j] *= inv; }
    float* dst = (dg < D_HALF)
        ? out + (size_t)row * D_HALF + dg
        : out + (size_t)N_TOK * D_HALF + (size_t)row * D_HALF + (dg - D_HALF);
    *reinterpret_cast<f32x4*>(dst)     = o0;
    *reinterpret_cast<f32x4*>(dst + 4) = o1;
}

extern "C" void kernel_launch(void* const* d_in, const int* in_sizes, int n_in,
                              void* d_out, int out_size, void* d_ws, size_t ws_size,
                              hipStream_t stream)
{
    const float* mag   = (const float*)d_in[0];
    const float* phase = (const float*)d_in[1];
    float* out = (float*)d_out;

    char* ws = (char*)d_ws;
    __hip_bfloat16* Kf = (__hip_bfloat16*)ws;                    // 2 MB
    __hip_bfloat16* Vf = Kf + (size_t)N_TOK * D_FULL;            // 2 MB
    __hip_bfloat16* Opart = (__hip_bfloat16*)(ws + 4u * 1024 * 1024);  // 8 MB
    float* Sp = (float*)(ws + 13u * 1024 * 1024);                // 128 KB

    precompute_kernel<<<768, 256, 0, stream>>>(mag, phase, Kf, Vf);
    attn_kernel<<<256, 512, 0, stream>>>((const short8*)Kf, (const short8*)Vf, Opart, Sp);
    merge4_kernel<<<512, 256, 0, stream>>>(Opart, Sp, out);
}